// Round 5
// baseline (614.511 us; speedup 1.0000x reference)
//
#include <hip/hip_runtime.h>
#include <cstdint>
#include <cstddef>

#define DEVI __device__ __forceinline__

typedef short bf16x8 __attribute__((ext_vector_type(8)));
typedef short bf16x4 __attribute__((ext_vector_type(4)));
typedef float f32x4  __attribute__((ext_vector_type(4)));

constexpr int H_  = 2048;
constexpr int NH  = 16;
constexpr int NKV = 4;
constexpr int HD  = 128;
constexpr int B_  = 4;
constexpr int QL  = 1024;
constexpr int CL  = 3072;
constexpr int KL  = 4096;   // CL + QL
constexpr float EPS = 1e-6f;
// SCALE * log2(e): folded into stored Q so attention softmax is bare exp2
constexpr float SCALE_LOG2E = 0.08838834764831845f * 1.4426950408889634f;

DEVI unsigned short f2bf(float x) {
  unsigned int u = __float_as_uint(x);
  u += 0x7FFFu + ((u >> 16) & 1u);   // RNE
  return (unsigned short)(u >> 16);
}
DEVI float bf2f(unsigned short u) {
  return __uint_as_float(((unsigned int)u) << 16);
}
// hardware packed f32->bf16 (RNE), 1 VALU instr
DEVI unsigned cvtpk(float a, float b) {
  unsigned r;
  asm("v_cvt_pk_bf16_f32 %0, %1, %2" : "=v"(r) : "v"(a), "v"(b));
  return r;
}
DEVI bf16x4 mk4(float a, float b, float c, float d) {
  union { unsigned u[2]; bf16x4 v; } r;
  r.u[0] = cvtpk(a, b);
  r.u[1] = cvtpk(c, d);
  return r.v;
}

DEVI void async16(const void* g, void* l) {
  __builtin_amdgcn_global_load_lds(
      (const __attribute__((address_space(1))) void*)g,
      (__attribute__((address_space(3))) void*)l, 16, 0, 0);
}

// ---------------------------------------------------------------------------
// prep: kvin_bf[b][pos][h] = bf16(concat(ctx, noise))   (b, KL, H)
// ---------------------------------------------------------------------------
__global__ __launch_bounds__(256)
void prep(const float* __restrict__ noise, const float* __restrict__ ctx,
          unsigned short* __restrict__ kvin) {
  const size_t t = (size_t)blockIdx.x * 256 + threadIdx.x;   // one 8-elem chunk
  const size_t e = t * 8;
  const int row = (int)(e / H_), col = (int)(e % H_);
  const int b = row >> 12, pos = row & 4095;
  const float* src = (pos < CL) ? ctx + ((size_t)(b * CL + pos)) * H_ + col
                                : noise + ((size_t)(b * QL + (pos - CL))) * H_ + col;
  float4 x = ((const float4*)src)[0], y = ((const float4*)src)[1];
  bf16x8 v;
  v[0] = (short)f2bf(x.x); v[1] = (short)f2bf(x.y);
  v[2] = (short)f2bf(x.z); v[3] = (short)f2bf(x.w);
  v[4] = (short)f2bf(y.x); v[5] = (short)f2bf(y.y);
  v[6] = (short)f2bf(y.z); v[7] = (short)f2bf(y.w);
  *(bf16x8*)(kvin + e) = v;
}

// ---------------------------------------------------------------------------
// Weight transpose + fp32 -> bf16:  in (K x N) fp32  ->  out (N x K) bf16
// ---------------------------------------------------------------------------
__global__ __launch_bounds__(256)
void wtrans(const float* __restrict__ in, unsigned short* __restrict__ out,
            int K, int N) {
  __shared__ float t[64][65];
  const int ktiles = K >> 6;
  const int kt = blockIdx.x % ktiles;
  const int nt = blockIdx.x / ktiles;
  {
    const int r = threadIdx.x >> 2, cs = threadIdx.x & 3;
    const float4* src = (const float4*)(in + (size_t)(kt * 64 + r) * N + nt * 64 + cs * 16);
    #pragma unroll
    for (int i = 0; i < 4; ++i) {
      float4 v = src[i];
      t[r][cs * 16 + i * 4 + 0] = v.x;
      t[r][cs * 16 + i * 4 + 1] = v.y;
      t[r][cs * 16 + i * 4 + 2] = v.z;
      t[r][cs * 16 + i * 4 + 3] = v.w;
    }
  }
  __syncthreads();
  {
    const int n = threadIdx.x >> 2, ks = threadIdx.x & 3;
    bf16x8 o0, o1;
    #pragma unroll
    for (int i = 0; i < 8; ++i) o0[i] = (short)f2bf(t[ks * 16 + i][n]);
    #pragma unroll
    for (int i = 0; i < 8; ++i) o1[i] = (short)f2bf(t[ks * 16 + 8 + i][n]);
    unsigned short* op = out + (size_t)(nt * 64 + n) * K + kt * 64 + ks * 16;
    *(bf16x8*)(op) = o0;
    *(bf16x8*)(op + 8) = o1;
  }
}

// ---------------------------------------------------------------------------
// m97-style GEMM, both operands bf16 via global_load_lds w/ XOR granule swizzle.
// C(M x N) = A(M x 2048) @ B(2048 x N), B given transposed (N x K) bf16.
// MODE 0: A=kvin rows (b,CL+q)  -> rmsnorm+rope, *SCALE_LOG2E -> q  (b,h,q,d)
// MODE 1: A=kvin                -> rmsnorm+rope -> k  (b,kv,p,d)
// MODE 2: A=kvin                -> transpose    -> vT (b,kv,d,p)
// MODE 3: A=attn_out bf16       -> fp32 d_out
// ---------------------------------------------------------------------------
template <int MODE>
__global__ __launch_bounds__(256)
void gemm2(const unsigned short* __restrict__ Abf,
           const unsigned short* __restrict__ Bt,
           const float* __restrict__ normw,
           const float* __restrict__ cosb, const float* __restrict__ sinb,
           unsigned short* __restrict__ outb, float* __restrict__ outf) {
  constexpr int M  = (MODE == 1 || MODE == 2) ? (B_ * KL) : (B_ * QL);
  constexpr int K  = H_;
  constexpr int MT = M / 128;

  __shared__ union U {
    struct { unsigned short a[128][64]; unsigned short b[128][64]; } st; // 32 KB
    unsigned short ct[128][138];                                         // 35.3 KB
  } sm;

  const int tid  = threadIdx.x;
  const int tm   = blockIdx.x % MT;
  const int tn   = blockIdx.x / MT;
  const int wid  = tid >> 6, lane = tid & 63, quad = lane >> 4, lm = lane & 15;
  const int wm   = wid >> 1, wn = wid & 1;

  f32x4 acc[4][4];
  #pragma unroll
  for (int i = 0; i < 4; ++i)
    #pragma unroll
    for (int j = 0; j < 4; ++j)
      #pragma unroll
      for (int r = 0; r < 4; ++r) acc[i][j][r] = 0.f;

  // staging pointers (per 16B granule; LDS side is linear: offset 16*idx)
  const unsigned short* agp[4];
  const unsigned short* bgp[4];
  #pragma unroll
  for (int i = 0; i < 4; ++i) {
    const int idx = i * 256 + tid;
    const int arow = idx >> 3, g = idx & 7, gg = g ^ (arow & 7);
    int grow;
    if constexpr (MODE == 0) {
      const int gmr = tm * 128 + arow;
      grow = (gmr >> 10) * KL + CL + (gmr & 1023);
    } else {
      grow = tm * 128 + arow;
    }
    agp[i] = Abf + (size_t)grow * K + gg * 8;
    bgp[i] = Bt + (size_t)(tn * 128 + arow) * K + gg * 8;
  }

  for (int kt = 0; kt < K / 64; ++kt) {
    __syncthreads();
    #pragma unroll
    for (int i = 0; i < 4; ++i) {
      async16(agp[i] + kt * 64, (char*)&sm.st.a[0][0] + (i * 256 + wid * 64) * 16);
      async16(bgp[i] + kt * 64, (char*)&sm.st.b[0][0] + (i * 256 + wid * 64) * 16);
    }
    __syncthreads();
    #pragma unroll
    for (int ks = 0; ks < 2; ++ks) {
      bf16x8 af[4], bfr[4];
      #pragma unroll
      for (int i = 0; i < 4; ++i) {
        const int swz = (ks * 4 + quad) ^ (lm & 7);
        af[i] = *(const bf16x8*)&sm.st.a[wm * 64 + i * 16 + lm][swz * 8];
      }
      #pragma unroll
      for (int j = 0; j < 4; ++j) {
        const int swz = (ks * 4 + quad) ^ (lm & 7);
        bfr[j] = *(const bf16x8*)&sm.st.b[wn * 64 + j * 16 + lm][swz * 8];
      }
      #pragma unroll
      for (int i = 0; i < 4; ++i)
        #pragma unroll
        for (int j = 0; j < 4; ++j)
          acc[i][j] = __builtin_amdgcn_mfma_f32_16x16x32_bf16(af[i], bfr[j], acc[i][j], 0, 0, 0);
    }
  }

  if constexpr (MODE == 3) {
    #pragma unroll
    for (int i = 0; i < 4; ++i)
      #pragma unroll
      for (int j = 0; j < 4; ++j) {
        const int row = tm * 128 + wm * 64 + i * 16 + quad * 4;
        const int col = tn * 128 + wn * 64 + j * 16 + lm;
        #pragma unroll
        for (int rr = 0; rr < 4; ++rr)
          outf[(size_t)(row + rr) * H_ + col] = acc[i][j][rr];
      }
    return;
  }

  // C tile -> LDS bf16
  __syncthreads();
  #pragma unroll
  for (int i = 0; i < 4; ++i)
    #pragma unroll
    for (int j = 0; j < 4; ++j)
      #pragma unroll
      for (int rr = 0; rr < 4; ++rr)
        sm.ct[wm * 64 + i * 16 + quad * 4 + rr][wn * 64 + j * 16 + lm] =
            f2bf(acc[i][j][rr]);
  __syncthreads();

  const int row2 = tid >> 1, half = tid & 1;
  if constexpr (MODE == 0 || MODE == 1) {
    const int gmr = tm * 128 + row2;
    int ci; size_t obase;
    if constexpr (MODE == 0) {
      const int b = gmr >> 10, pos = gmr & 1023;
      ci = (b * KL + CL + pos) * HD;
      obase = ((size_t)((b * NH + tn) * QL + pos)) * HD;
    } else {
      const int b = gmr >> 12, pos = gmr & 4095;
      ci = (b * KL + pos) * HD;
      obase = ((size_t)((b * NKV + tn) * KL + pos)) * HD;
    }
    float ss = 0.f;
    for (int d = half * 64; d < half * 64 + 64; ++d) {
      float v = bf2f(sm.ct[row2][d]);
      ss += v * v;
    }
    ss += __shfl_xor(ss, 1);
    const float rinv = rsqrtf(ss * (1.0f / 128.0f) + EPS);
    constexpr float OSC = (MODE == 0) ? SCALE_LOG2E : 1.0f;
    #pragma unroll
    for (int d8 = 0; d8 < 8; ++d8) {
      bf16x8 v;
      #pragma unroll
      for (int j = 0; j < 8; ++j) {
        const int d = half * 64 + d8 * 8 + j;
        const float x  = bf2f(sm.ct[row2][d])      * rinv * normw[d];
        const float xo = bf2f(sm.ct[row2][d ^ 64]) * rinv * normw[d ^ 64];
        const float rot = (d < 64) ? -xo : xo;
        v[j] = (short)f2bf((x * cosb[ci + d] + rot * sinb[ci + d]) * OSC);
      }
      *(bf16x8*)(outb + obase + half * 64 + d8 * 8) = v;
    }
  } else {
    // MODE 2: V^T  (b, kv, d, pos)
    const int d = row2;
    const int b = (tm * 128) >> 12;
    const int posBase = ((tm * 128) & 4095) + half * 64;
    const size_t obase = ((size_t)((b * NKV + tn) * HD + d)) * KL + posBase;
    #pragma unroll
    for (int k8 = 0; k8 < 8; ++k8) {
      bf16x8 v;
      #pragma unroll
      for (int j = 0; j < 8; ++j)
        v[j] = (short)sm.ct[half * 64 + k8 * 8 + j][d];
      *(bf16x8*)(outb + obase + k8 * 8) = v;
    }
  }
}

// ---------------------------------------------------------------------------
// Flash attention v5 (resubmit: round-4 bench was an infra failure, kernel
// audited clean -- bounds, sync ladder, and relayout all re-verified).
// W=4: block = (b,h) x 256 q rows, 4 waves x 64 q (4 16-row tiles per wave).
// Grid = 64 bh x 4 qblk = 256 blocks = 1 block/CU.
// LDS lesson (r1 vs r0 vs r3): LDS read traffic = waves x iters x 32KB; only
// W (q rows/wave) reduces it.  W=4 halves per-CU LDS reads vs r3 (82->41us),
// dropping LDS below the 66us bf16-MFMA floor.  r2 proved this occupancy
// point (1 wave/SIMD) sustains ~88% sum-pipe efficiency.
// P^T relayout is PURE VALU (no ds_swizzle/cndmask): per t,
//   permlane32_swap(A,B):  A'=[A.lo32|B.lo32], B'=[A.hi32|B.hi32]
//   permlane16_swap(A',B'): A''=[A'.g0,B'.g0,A'.g2,B'.g2] -> u0 (u1)
//                           B''=[A'.g1,B'.g1,A'.g3,B'.g3] -> u2 (u3)
// giving the K=32 B-frag (kpos quad*8+e) in 4 instrs.  P packing via
// v_cvt_pk_bf16_f32 (1 instr vs 3).  Double-buffered K/V staging, counted
// vmcnt(8) + raw s_barrier.  No-max softmax (|s|<=16.3 in exp2 domain).
// ---------------------------------------------------------------------------
__global__ __launch_bounds__(256, 1)
void attn2(const unsigned short* __restrict__ qb,
           const unsigned short* __restrict__ kb,
           const unsigned short* __restrict__ vtb,
           unsigned short* __restrict__ ao) {
  __shared__ unsigned short kl[2][64][128];   // 2 x 16 KB : K tile (kpos x d)
  __shared__ unsigned short vl[2][128][64];   // 2 x 16 KB : V^T tile (d x kpos)

  const int tid = threadIdx.x;
  const int wave = tid >> 6, lane = tid & 63, quad = lane >> 4, lm = lane & 15;
  const int qblk = blockIdx.x & 3;
  const int bh = blockIdx.x >> 2;
  const int b = bh >> 4, h = bh & 15, kvh = h >> 2;
  const int q0 = qblk * 256 + wave * 64;   // this wave's 64 q rows (4 tiles)

  // Q fragments (already scaled by SCALE_LOG2E at projection time)
  bf16x8 qf[4][4];
  const unsigned short* qbase = qb + ((size_t)((b * NH + h) * QL + q0)) * HD;
  #pragma unroll
  for (int t = 0; t < 4; ++t)
    #pragma unroll
    for (int kq = 0; kq < 4; ++kq)
      qf[t][kq] = *(const bf16x8*)(qbase + (t * 16 + lm) * HD + kq * 32 + quad * 8);

  f32x4 o[4][8];
  float li[4] = {0.f, 0.f, 0.f, 0.f};
  #pragma unroll
  for (int t = 0; t < 4; ++t)
    #pragma unroll
    for (int dt = 0; dt < 8; ++dt)
      #pragma unroll
      for (int rr = 0; rr < 4; ++rr) o[t][dt][rr] = 0.f;

  const unsigned short* kbase = kb + ((size_t)(b * NKV + kvh)) * KL * HD;
  const unsigned short* vbase = vtb + ((size_t)(b * NKV + kvh)) * HD * KL;

  // per-thread staging granule (XOR swizzle; granule i at fixed XOR because
  // row advances by multiples of 8 across i)
  const int krow0 = tid >> 4, kgc = tid & 15;
  const int kgg = (kgc & 8) | ((kgc & 7) ^ (krow0 & 7));
  const unsigned short* kgp0 = kbase + (size_t)krow0 * HD + kgg * 8;
  const int vrow0 = tid >> 3;
  const int vgv = (tid & 7) ^ (vrow0 & 7);
  const unsigned short* vgp0 = vbase + (size_t)vrow0 * KL + vgv * 8;

  auto stage = [&](int bufi, int ktt) {
    #pragma unroll
    for (int i = 0; i < 4; ++i) {
      async16(kgp0 + (size_t)ktt * (64 * HD) + i * (16 * HD),
              (char*)&kl[bufi][0][0] + (i * 256 + wave * 64) * 16);
      async16(vgp0 + (size_t)ktt * 64 + i * (32 * KL),
              (char*)&vl[bufi][0][0] + (i * 256 + wave * 64) * 16);
    }
  };

  stage(0, 0);
  for (int kt = 0; kt < KL / 64; ++kt) {
    const int cur = kt & 1;
    if (kt + 1 < KL / 64) {
      stage(cur ^ 1, kt + 1);                            // 8 loads in flight
      asm volatile("s_waitcnt vmcnt(8)" ::: "memory");   // wait only cur's 8
    } else {
      asm volatile("s_waitcnt vmcnt(0)" ::: "memory");
    }
    __builtin_amdgcn_s_barrier();

    #pragma unroll
    for (int j = 0; j < 2; ++j) {        // 32-kpos half of the tile
      // K fragments for both 16-kpos subtiles (8 x b128)
      bf16x8 kf[2][4];
      #pragma unroll
      for (int sub = 0; sub < 2; ++sub) {
        const int nt = j * 2 + sub;
        #pragma unroll
        for (int kq = 0; kq < 4; ++kq) {
          const int gc = kq * 4 + quad;
          const int swz = (gc & 8) | ((gc & 7) ^ (lm & 7));
          kf[sub][kq] = *(const bf16x8*)&kl[cur][nt * 16 + lm][swz * 8];
        }
      }
      // QK^T: 32 MFMA, 8 independent accumulator chains
      f32x4 s[4][2];
      #pragma unroll
      for (int t = 0; t < 4; ++t)
        #pragma unroll
        for (int sub = 0; sub < 2; ++sub)
          #pragma unroll
          for (int rr = 0; rr < 4; ++rr) s[t][sub][rr] = 0.f;
      __builtin_amdgcn_s_setprio(1);
      #pragma unroll
      for (int kq = 0; kq < 4; ++kq)
        #pragma unroll
        for (int sub = 0; sub < 2; ++sub)
          #pragma unroll
          for (int t = 0; t < 4; ++t)
            s[t][sub] = __builtin_amdgcn_mfma_f32_16x16x32_bf16(
                kf[sub][kq], qf[t][kq], s[t][sub], 0, 0, 0);
      __builtin_amdgcn_s_setprio(0);

      // V^T fragments (8 x b128, shared across t) -- issue early so the
      // lgkm latency hides under the softmax VALU below
      bf16x8 vfr[8];
      #pragma unroll
      for (int dt = 0; dt < 8; ++dt) {
        const int gv = (j * 4 + quad) ^ (lm & 7);
        vfr[dt] = *(const bf16x8*)&vl[cur][dt * 16 + lm][gv * 8];
      }

      // softmax + pure-VALU relayout -> P[t] = K=32 B-frag
      bf16x8 P[4];
      #pragma unroll
      for (int t = 0; t < 4; ++t) {
        float e00 = __builtin_amdgcn_exp2f(s[t][0][0]);
        float e01 = __builtin_amdgcn_exp2f(s[t][0][1]);
        float e02 = __builtin_amdgcn_exp2f(s[t][0][2]);
        float e03 = __builtin_amdgcn_exp2f(s[t][0][3]);
        float e10 = __builtin_amdgcn_exp2f(s[t][1][0]);
        float e11 = __builtin_amdgcn_exp2f(s[t][1][1]);
        float e12 = __builtin_amdgcn_exp2f(s[t][1][2]);
        float e13 = __builtin_amdgcn_exp2f(s[t][1][3]);
        li[t] += ((e00 + e01) + (e02 + e03)) + ((e10 + e11) + (e12 + e13));
        unsigned A0 = cvtpk(e00, e01), A1 = cvtpk(e02, e03);
        unsigned B0 = cvtpk(e10, e11), B1 = cvtpk(e12, e13);
        asm volatile("v_permlane32_swap_b32 %0, %1" : "+v"(A0), "+v"(B0));
        asm volatile("v_permlane32_swap_b32 %0, %1" : "+v"(A1), "+v"(B1));
        asm volatile("v_permlane16_swap_b32 %0, %1" : "+v"(A0), "+v"(B0));
        asm volatile("v_permlane16_swap_b32 %0, %1" : "+v"(A1), "+v"(B1));
        union { unsigned u[4]; bf16x8 v; } up;
        up.u[0] = A0; up.u[1] = A1; up.u[2] = B0; up.u[3] = B1;
        P[t] = up.v;
      }

      // PV: 32 MFMA at full rate
      __builtin_amdgcn_s_setprio(1);
      #pragma unroll
      for (int dt = 0; dt < 8; ++dt)
        #pragma unroll
        for (int t = 0; t < 4; ++t)
          o[t][dt] = __builtin_amdgcn_mfma_f32_16x16x32_bf16(
              vfr[dt], P[t], o[t][dt], 0, 0, 0);
      __builtin_amdgcn_s_setprio(0);
    }
    __builtin_amdgcn_s_barrier();
  }

  #pragma unroll
  for (int t = 0; t < 4; ++t) {
    float l = li[t];
    l += __shfl_xor(l, 16);
    l += __shfl_xor(l, 32);
    const float inv = 1.0f / l;
    const size_t rowbase = ((size_t)(b * QL + q0 + t * 16 + lm)) * (NH * HD) + h * HD;
    #pragma unroll
    for (int dt = 0; dt < 8; ++dt) {
      bf16x4 v = mk4(o[t][dt][0] * inv, o[t][dt][1] * inv,
                     o[t][dt][2] * inv, o[t][dt][3] * inv);
      *(bf16x4*)(ao + rowbase + dt * 16 + quad * 4) = v;
    }
  }
}

// ---------------------------------------------------------------------------
extern "C" void kernel_launch(void* const* d_in, const int* in_sizes, int n_in,
                              void* d_out, int out_size, void* d_ws, size_t ws_size,
                              hipStream_t stream) {
  const float* noise = (const float*)d_in[0];
  const float* ctx   = (const float*)d_in[1];
  const float* cosb  = (const float*)d_in[2];
  const float* sinb  = (const float*)d_in[3];
  const float* Wq    = (const float*)d_in[4];
  const float* Wk    = (const float*)d_in[5];
  const float* Wv    = (const float*)d_in[6];
  const float* Wo    = (const float*)d_in[7];
  const float* qn    = (const float*)d_in[8];
  const float* kn    = (const float*)d_in[9];
  float* out = (float*)d_out;

  char* ws = (char*)d_ws;
  // kvin: 64 MB [0,64M).  aob aliases kvin[0:16M) (kvin dead after V-proj).
  unsigned short* kvin = (unsigned short*)(ws);
  unsigned short* aob  = (unsigned short*)(ws);
  unsigned short* WqT  = (unsigned short*)(ws + 67108864);            //  8 MB
  unsigned short* WkT  = (unsigned short*)(ws + 67108864 + 8388608);  //  2 MB
  unsigned short* WvT  = (unsigned short*)(ws + 67108864 + 10485760); //  2 MB
  unsigned short* WoT  = (unsigned short*)(ws + 67108864 + 12582912); //  8 MB
  unsigned short* qbuf = (unsigned short*)(ws + 67108864 + 20971520); // 16 MB
  unsigned short* kbuf = (unsigned short*)(ws + 67108864 + 37748736); // 16 MB
  unsigned short* vtb  = (unsigned short*)(ws + 67108864 + 54525952); // 16 MB (total 132 MB)

  prep<<<dim3((B_ * KL * H_) / 8 / 256), dim3(256), 0, stream>>>(noise, ctx, kvin);

  wtrans<<<dim3(1024), dim3(256), 0, stream>>>(Wq, WqT, 2048, 2048);
  wtrans<<<dim3(256),  dim3(256), 0, stream>>>(Wk, WkT, 2048, 512);
  wtrans<<<dim3(256),  dim3(256), 0, stream>>>(Wv, WvT, 2048, 512);
  wtrans<<<dim3(1024), dim3(256), 0, stream>>>(Wo, WoT, 2048, 2048);

  gemm2<0><<<dim3(32 * 16), dim3(256), 0, stream>>>(
      kvin, WqT, qn, cosb, sinb, qbuf, nullptr);
  gemm2<1><<<dim3(128 * 4), dim3(256), 0, stream>>>(
      kvin, WkT, kn, cosb, sinb, kbuf, nullptr);
  gemm2<2><<<dim3(128 * 4), dim3(256), 0, stream>>>(
      kvin, WvT, nullptr, nullptr, nullptr, vtb, nullptr);

  attn2<<<dim3(256), dim3(256), 0, stream>>>(qbuf, kbuf, vtb, aob);

  gemm2<3><<<dim3(32 * 16), dim3(256), 0, stream>>>(
      aob, WoT, nullptr, nullptr, nullptr, nullptr, out);
}

// Round 6
// 580.028 us; speedup vs baseline: 1.0595x; 1.0595x over previous
//
#include <hip/hip_runtime.h>
#include <cstdint>
#include <cstddef>

#define DEVI __device__ __forceinline__

typedef short bf16x8 __attribute__((ext_vector_type(8)));
typedef short bf16x4 __attribute__((ext_vector_type(4)));
typedef float f32x4  __attribute__((ext_vector_type(4)));

constexpr int H_  = 2048;
constexpr int NH  = 16;
constexpr int NKV = 4;
constexpr int HD  = 128;
constexpr int B_  = 4;
constexpr int QL  = 1024;
constexpr int CL  = 3072;
constexpr int KL  = 4096;   // CL + QL
constexpr float EPS = 1e-6f;
// SCALE * log2(e): folded into stored Q so attention softmax is bare exp2
constexpr float SCALE_LOG2E = 0.08838834764831845f * 1.4426950408889634f;

DEVI unsigned short f2bf(float x) {
  unsigned int u = __float_as_uint(x);
  u += 0x7FFFu + ((u >> 16) & 1u);   // RNE
  return (unsigned short)(u >> 16);
}
DEVI float bf2f(unsigned short u) {
  return __uint_as_float(((unsigned int)u) << 16);
}
// hardware packed f32->bf16 (RNE), 1 VALU instr
DEVI unsigned cvtpk(float a, float b) {
  unsigned r;
  asm("v_cvt_pk_bf16_f32 %0, %1, %2" : "=v"(r) : "v"(a), "v"(b));
  return r;
}
DEVI bf16x4 mk4(float a, float b, float c, float d) {
  union { unsigned u[2]; bf16x4 v; } r;
  r.u[0] = cvtpk(a, b);
  r.u[1] = cvtpk(c, d);
  return r.v;
}

DEVI void async16(const void* g, void* l) {
  __builtin_amdgcn_global_load_lds(
      (const __attribute__((address_space(1))) void*)g,
      (__attribute__((address_space(3))) void*)l, 16, 0, 0);
}

// ---------------------------------------------------------------------------
// prep: kvin_bf[b][pos][h] = bf16(concat(ctx, noise))   (b, KL, H)
// ---------------------------------------------------------------------------
__global__ __launch_bounds__(256)
void prep(const float* __restrict__ noise, const float* __restrict__ ctx,
          unsigned short* __restrict__ kvin) {
  const size_t t = (size_t)blockIdx.x * 256 + threadIdx.x;   // one 8-elem chunk
  const size_t e = t * 8;
  const int row = (int)(e / H_), col = (int)(e % H_);
  const int b = row >> 12, pos = row & 4095;
  const float* src = (pos < CL) ? ctx + ((size_t)(b * CL + pos)) * H_ + col
                                : noise + ((size_t)(b * QL + (pos - CL))) * H_ + col;
  float4 x = ((const float4*)src)[0], y = ((const float4*)src)[1];
  bf16x8 v;
  v[0] = (short)f2bf(x.x); v[1] = (short)f2bf(x.y);
  v[2] = (short)f2bf(x.z); v[3] = (short)f2bf(x.w);
  v[4] = (short)f2bf(y.x); v[5] = (short)f2bf(y.y);
  v[6] = (short)f2bf(y.z); v[7] = (short)f2bf(y.w);
  *(bf16x8*)(kvin + e) = v;
}

// ---------------------------------------------------------------------------
// Weight transpose + fp32 -> bf16:  in (K x N) fp32  ->  out (N x K) bf16
// ---------------------------------------------------------------------------
__global__ __launch_bounds__(256)
void wtrans(const float* __restrict__ in, unsigned short* __restrict__ out,
            int K, int N) {
  __shared__ float t[64][65];
  const int ktiles = K >> 6;
  const int kt = blockIdx.x % ktiles;
  const int nt = blockIdx.x / ktiles;
  {
    const int r = threadIdx.x >> 2, cs = threadIdx.x & 3;
    const float4* src = (const float4*)(in + (size_t)(kt * 64 + r) * N + nt * 64 + cs * 16);
    #pragma unroll
    for (int i = 0; i < 4; ++i) {
      float4 v = src[i];
      t[r][cs * 16 + i * 4 + 0] = v.x;
      t[r][cs * 16 + i * 4 + 1] = v.y;
      t[r][cs * 16 + i * 4 + 2] = v.z;
      t[r][cs * 16 + i * 4 + 3] = v.w;
    }
  }
  __syncthreads();
  {
    const int n = threadIdx.x >> 2, ks = threadIdx.x & 3;
    bf16x8 o0, o1;
    #pragma unroll
    for (int i = 0; i < 8; ++i) o0[i] = (short)f2bf(t[ks * 16 + i][n]);
    #pragma unroll
    for (int i = 0; i < 8; ++i) o1[i] = (short)f2bf(t[ks * 16 + 8 + i][n]);
    unsigned short* op = out + (size_t)(nt * 64 + n) * K + kt * 64 + ks * 16;
    *(bf16x8*)(op) = o0;
    *(bf16x8*)(op + 8) = o1;
  }
}

// ---------------------------------------------------------------------------
// m97-style GEMM, both operands bf16 via global_load_lds w/ XOR granule swizzle.
// C(M x N) = A(M x 2048) @ B(2048 x N), B given transposed (N x K) bf16.
// MODE 0: A=kvin rows (b,CL+q)  -> rmsnorm+rope, *SCALE_LOG2E -> q  (b,h,q,d)
// MODE 1: A=kvin                -> rmsnorm+rope -> k  (b,kv,p,d)
// MODE 2: A=kvin                -> transpose    -> vT (b,kv,d,p)
// MODE 3: A=attn_out bf16       -> fp32 d_out
// r6: ct stride 138->136 (16B-aligned rows) + vectorized MODE0/1 epilogue
// (bf16x8 LDS reads, float4 cos/sin loads) -- was 128 scalar b16 LDS reads +
// 256 scalar global f32 loads per thread (Common-mistake #2).
// ---------------------------------------------------------------------------
template <int MODE>
__global__ __launch_bounds__(256)
void gemm2(const unsigned short* __restrict__ Abf,
           const unsigned short* __restrict__ Bt,
           const float* __restrict__ normw,
           const float* __restrict__ cosb, const float* __restrict__ sinb,
           unsigned short* __restrict__ outb, float* __restrict__ outf) {
  constexpr int M  = (MODE == 1 || MODE == 2) ? (B_ * KL) : (B_ * QL);
  constexpr int K  = H_;
  constexpr int MT = M / 128;

  __shared__ union alignas(16) U {
    struct { unsigned short a[128][64]; unsigned short b[128][64]; } st; // 32 KB
    unsigned short ct[128][136];                                         // 34 KB
  } sm;

  const int tid  = threadIdx.x;
  const int tm   = blockIdx.x % MT;
  const int tn   = blockIdx.x / MT;
  const int wid  = tid >> 6, lane = tid & 63, quad = lane >> 4, lm = lane & 15;
  const int wm   = wid >> 1, wn = wid & 1;

  f32x4 acc[4][4];
  #pragma unroll
  for (int i = 0; i < 4; ++i)
    #pragma unroll
    for (int j = 0; j < 4; ++j)
      #pragma unroll
      for (int r = 0; r < 4; ++r) acc[i][j][r] = 0.f;

  // staging pointers (per 16B granule; LDS side is linear: offset 16*idx)
  const unsigned short* agp[4];
  const unsigned short* bgp[4];
  #pragma unroll
  for (int i = 0; i < 4; ++i) {
    const int idx = i * 256 + tid;
    const int arow = idx >> 3, g = idx & 7, gg = g ^ (arow & 7);
    int grow;
    if constexpr (MODE == 0) {
      const int gmr = tm * 128 + arow;
      grow = (gmr >> 10) * KL + CL + (gmr & 1023);
    } else {
      grow = tm * 128 + arow;
    }
    agp[i] = Abf + (size_t)grow * K + gg * 8;
    bgp[i] = Bt + (size_t)(tn * 128 + arow) * K + gg * 8;
  }

  for (int kt = 0; kt < K / 64; ++kt) {
    __syncthreads();
    #pragma unroll
    for (int i = 0; i < 4; ++i) {
      async16(agp[i] + kt * 64, (char*)&sm.st.a[0][0] + (i * 256 + wid * 64) * 16);
      async16(bgp[i] + kt * 64, (char*)&sm.st.b[0][0] + (i * 256 + wid * 64) * 16);
    }
    __syncthreads();
    #pragma unroll
    for (int ks = 0; ks < 2; ++ks) {
      bf16x8 af[4], bfr[4];
      #pragma unroll
      for (int i = 0; i < 4; ++i) {
        const int swz = (ks * 4 + quad) ^ (lm & 7);
        af[i] = *(const bf16x8*)&sm.st.a[wm * 64 + i * 16 + lm][swz * 8];
      }
      #pragma unroll
      for (int j = 0; j < 4; ++j) {
        const int swz = (ks * 4 + quad) ^ (lm & 7);
        bfr[j] = *(const bf16x8*)&sm.st.b[wn * 64 + j * 16 + lm][swz * 8];
      }
      #pragma unroll
      for (int i = 0; i < 4; ++i)
        #pragma unroll
        for (int j = 0; j < 4; ++j)
          acc[i][j] = __builtin_amdgcn_mfma_f32_16x16x32_bf16(af[i], bfr[j], acc[i][j], 0, 0, 0);
    }
  }

  if constexpr (MODE == 3) {
    #pragma unroll
    for (int i = 0; i < 4; ++i)
      #pragma unroll
      for (int j = 0; j < 4; ++j) {
        const int row = tm * 128 + wm * 64 + i * 16 + quad * 4;
        const int col = tn * 128 + wn * 64 + j * 16 + lm;
        #pragma unroll
        for (int rr = 0; rr < 4; ++rr)
          outf[(size_t)(row + rr) * H_ + col] = acc[i][j][rr];
      }
    return;
  }

  // C tile -> LDS bf16
  __syncthreads();
  #pragma unroll
  for (int i = 0; i < 4; ++i)
    #pragma unroll
    for (int j = 0; j < 4; ++j)
      #pragma unroll
      for (int rr = 0; rr < 4; ++rr)
        sm.ct[wm * 64 + i * 16 + quad * 4 + rr][wn * 64 + j * 16 + lm] =
            f2bf(acc[i][j][rr]);
  __syncthreads();

  const int row2 = tid >> 1, half = tid & 1;
  if constexpr (MODE == 0 || MODE == 1) {
    const int gmr = tm * 128 + row2;
    int ci; size_t obase;
    if constexpr (MODE == 0) {
      const int b = gmr >> 10, pos = gmr & 1023;
      ci = (b * KL + CL + pos) * HD;
      obase = ((size_t)((b * NH + tn) * QL + pos)) * HD;
    } else {
      const int b = gmr >> 12, pos = gmr & 4095;
      ci = (b * KL + pos) * HD;
      obase = ((size_t)((b * NKV + tn) * KL + pos)) * HD;
    }
    const unsigned short* ctr = &sm.ct[row2][0];
    float ss = 0.f;
    #pragma unroll
    for (int i = 0; i < 8; ++i) {
      bf16x8 v = *(const bf16x8*)(ctr + half * 64 + i * 8);
      #pragma unroll
      for (int jj = 0; jj < 8; ++jj) {
        const float f = bf2f((unsigned short)v[jj]);
        ss += f * f;
      }
    }
    ss += __shfl_xor(ss, 1);
    const float rinv = rsqrtf(ss * (1.0f / 128.0f) + EPS);
    constexpr float OSC = (MODE == 0) ? SCALE_LOG2E : 1.0f;
    #pragma unroll
    for (int d8 = 0; d8 < 8; ++d8) {
      const int dbase = half * 64 + d8 * 8;
      bf16x8 xv = *(const bf16x8*)(ctr + dbase);
      bf16x8 xo = *(const bf16x8*)(ctr + (dbase ^ 64));
      union { float4 v[2]; float f[8]; } cc, sn;
      cc.v[0] = *(const float4*)(cosb + ci + dbase);
      cc.v[1] = *(const float4*)(cosb + ci + dbase + 4);
      sn.v[0] = *(const float4*)(sinb + ci + dbase);
      sn.v[1] = *(const float4*)(sinb + ci + dbase + 4);
      bf16x8 outv;
      #pragma unroll
      for (int jj = 0; jj < 8; ++jj) {
        const float x  = bf2f((unsigned short)xv[jj]) * rinv * normw[dbase + jj];
        const float xr = bf2f((unsigned short)xo[jj]) * rinv * normw[(dbase ^ 64) + jj];
        const float rot = (half == 0) ? -xr : xr;   // d<64 iff half==0
        outv[jj] = (short)f2bf((x * cc.f[jj] + rot * sn.f[jj]) * OSC);
      }
      *(bf16x8*)(outb + obase + dbase) = outv;
    }
  } else {
    // MODE 2: V^T  (b, kv, d, pos)
    const int d = row2;
    const int b = (tm * 128) >> 12;
    const int posBase = ((tm * 128) & 4095) + half * 64;
    const size_t obase = ((size_t)((b * NKV + tn) * HD + d)) * KL + posBase;
    #pragma unroll
    for (int k8 = 0; k8 < 8; ++k8) {
      bf16x8 v;
      #pragma unroll
      for (int j = 0; j < 8; ++j)
        v[j] = (short)sm.ct[half * 64 + k8 * 8 + j][d];
      *(bf16x8*)(outb + obase + k8 * 8) = v;
    }
  }
}

// ---------------------------------------------------------------------------
// Flash attention v6 = r3 structure + r5's HW-verified VALU relayout.
// Block = (b,h) x 128 q rows; 4 waves x 32 q (W=2).  Grid 512 = 2 blocks/CU,
// 2 waves/SIMD.  Occupancy lesson (r2/r3/r5): sum-pipe efficiency is ~87% at
// 2 waves/SIMD but only ~65-75% at 1 wave/SIMD (intra-wave dependency stalls
// exposed) -- and LDS traffic scales as waves x 32KB x iters, so W=2 at
// 2 waves/SIMD is the measured sweet spot (r3: 166us).
// PV at full rate (16x16x32): P^T relayout from S^T C-layout is PURE VALU --
// per t: 4x v_cvt_pk_bf16_f32, 2x v_permlane32_swap, 2x v_permlane16_swap
// (verified on HW in r5, same absmax).  No ds_swizzle, no cndmask.
// Double-buffered K/V staging, counted vmcnt(8) + raw s_barrier.
// No-max softmax (|s|<=16.3 in exp2 domain, bounded by RMSNorm).
// ---------------------------------------------------------------------------
__global__ __launch_bounds__(256, 2)
void attn2(const unsigned short* __restrict__ qb,
           const unsigned short* __restrict__ kb,
           const unsigned short* __restrict__ vtb,
           unsigned short* __restrict__ ao) {
  __shared__ unsigned short kl[2][64][128];   // 2 x 16 KB : K tile (kpos x d)
  __shared__ unsigned short vl[2][128][64];   // 2 x 16 KB : V^T tile (d x kpos)

  const int tid = threadIdx.x;
  const int wave = tid >> 6, lane = tid & 63, quad = lane >> 4, lm = lane & 15;
  const int qblk = blockIdx.x & 7;
  const int bh = blockIdx.x >> 3;
  const int b = bh >> 4, h = bh & 15, kvh = h >> 2;
  const int q0 = qblk * 128 + wave * 32;

  // Q fragments (already scaled by SCALE_LOG2E at projection time)
  bf16x8 qf[2][4];
  const unsigned short* qbase = qb + ((size_t)((b * NH + h) * QL + q0)) * HD;
  #pragma unroll
  for (int t = 0; t < 2; ++t)
    #pragma unroll
    for (int kq = 0; kq < 4; ++kq)
      qf[t][kq] = *(const bf16x8*)(qbase + (t * 16 + lm) * HD + kq * 32 + quad * 8);

  f32x4 o[2][8];
  float li[2] = {0.f, 0.f};
  #pragma unroll
  for (int t = 0; t < 2; ++t)
    #pragma unroll
    for (int dt = 0; dt < 8; ++dt)
      #pragma unroll
      for (int rr = 0; rr < 4; ++rr) o[t][dt][rr] = 0.f;

  const unsigned short* kbase = kb + ((size_t)(b * NKV + kvh)) * KL * HD;
  const unsigned short* vbase = vtb + ((size_t)(b * NKV + kvh)) * HD * KL;

  // per-thread staging granule (XOR swizzle; granule i at fixed XOR because
  // row advances by multiples of 8 across i)
  const int krow0 = tid >> 4, kgc = tid & 15;
  const int kgg = (kgc & 8) | ((kgc & 7) ^ (krow0 & 7));
  const unsigned short* kgp0 = kbase + (size_t)krow0 * HD + kgg * 8;
  const int vrow0 = tid >> 3;
  const int vgv = (tid & 7) ^ (vrow0 & 7);
  const unsigned short* vgp0 = vbase + (size_t)vrow0 * KL + vgv * 8;

  auto stage = [&](int bufi, int ktt) {
    #pragma unroll
    for (int i = 0; i < 4; ++i) {
      async16(kgp0 + (size_t)ktt * (64 * HD) + i * (16 * HD),
              (char*)&kl[bufi][0][0] + (i * 256 + wave * 64) * 16);
      async16(vgp0 + (size_t)ktt * 64 + i * (32 * KL),
              (char*)&vl[bufi][0][0] + (i * 256 + wave * 64) * 16);
    }
  };

  stage(0, 0);
  for (int kt = 0; kt < KL / 64; ++kt) {
    const int cur = kt & 1;
    if (kt + 1 < KL / 64) {
      stage(cur ^ 1, kt + 1);                            // 8 loads in flight
      asm volatile("s_waitcnt vmcnt(8)" ::: "memory");   // wait only cur's 8
    } else {
      asm volatile("s_waitcnt vmcnt(0)" ::: "memory");
    }
    __builtin_amdgcn_s_barrier();

    #pragma unroll
    for (int j = 0; j < 2; ++j) {        // 32-kpos half of the tile
      // K fragments for both 16-kpos subtiles (8 x b128)
      bf16x8 kf[2][4];
      #pragma unroll
      for (int sub = 0; sub < 2; ++sub) {
        const int nt = j * 2 + sub;
        #pragma unroll
        for (int kq = 0; kq < 4; ++kq) {
          const int gc = kq * 4 + quad;
          const int swz = (gc & 8) | ((gc & 7) ^ (lm & 7));
          kf[sub][kq] = *(const bf16x8*)&kl[cur][nt * 16 + lm][swz * 8];
        }
      }
      // QK^T: 16 MFMA, 4 independent accumulator chains
      f32x4 s[2][2];
      #pragma unroll
      for (int t = 0; t < 2; ++t)
        #pragma unroll
        for (int sub = 0; sub < 2; ++sub)
          #pragma unroll
          for (int rr = 0; rr < 4; ++rr) s[t][sub][rr] = 0.f;
      __builtin_amdgcn_s_setprio(1);
      #pragma unroll
      for (int kq = 0; kq < 4; ++kq)
        #pragma unroll
        for (int sub = 0; sub < 2; ++sub)
          #pragma unroll
          for (int t = 0; t < 2; ++t)
            s[t][sub] = __builtin_amdgcn_mfma_f32_16x16x32_bf16(
                kf[sub][kq], qf[t][kq], s[t][sub], 0, 0, 0);
      __builtin_amdgcn_s_setprio(0);

      // V^T fragments (8 x b128, shared across t) -- issued before softmax
      // so lgkm latency hides under the VALU below
      bf16x8 vfr[8];
      #pragma unroll
      for (int dt = 0; dt < 8; ++dt) {
        const int gv = (j * 4 + quad) ^ (lm & 7);
        vfr[dt] = *(const bf16x8*)&vl[cur][dt * 16 + lm][gv * 8];
      }

      // softmax + pure-VALU relayout -> P[t] = K=32 B-frag
      bf16x8 P[2];
      #pragma unroll
      for (int t = 0; t < 2; ++t) {
        float e00 = __builtin_amdgcn_exp2f(s[t][0][0]);
        float e01 = __builtin_amdgcn_exp2f(s[t][0][1]);
        float e02 = __builtin_amdgcn_exp2f(s[t][0][2]);
        float e03 = __builtin_amdgcn_exp2f(s[t][0][3]);
        float e10 = __builtin_amdgcn_exp2f(s[t][1][0]);
        float e11 = __builtin_amdgcn_exp2f(s[t][1][1]);
        float e12 = __builtin_amdgcn_exp2f(s[t][1][2]);
        float e13 = __builtin_amdgcn_exp2f(s[t][1][3]);
        li[t] += ((e00 + e01) + (e02 + e03)) + ((e10 + e11) + (e12 + e13));
        unsigned A0 = cvtpk(e00, e01), A1 = cvtpk(e02, e03);
        unsigned B0 = cvtpk(e10, e11), B1 = cvtpk(e12, e13);
        asm volatile("v_permlane32_swap_b32 %0, %1" : "+v"(A0), "+v"(B0));
        asm volatile("v_permlane32_swap_b32 %0, %1" : "+v"(A1), "+v"(B1));
        asm volatile("v_permlane16_swap_b32 %0, %1" : "+v"(A0), "+v"(B0));
        asm volatile("v_permlane16_swap_b32 %0, %1" : "+v"(A1), "+v"(B1));
        union { unsigned u[4]; bf16x8 v; } up;
        up.u[0] = A0; up.u[1] = A1; up.u[2] = B0; up.u[3] = B1;
        P[t] = up.v;
      }

      // PV: 16 MFMA at full rate
      __builtin_amdgcn_s_setprio(1);
      #pragma unroll
      for (int dt = 0; dt < 8; ++dt)
        #pragma unroll
        for (int t = 0; t < 2; ++t)
          o[t][dt] = __builtin_amdgcn_mfma_f32_16x16x32_bf16(
              vfr[dt], P[t], o[t][dt], 0, 0, 0);
      __builtin_amdgcn_s_setprio(0);
    }
    __builtin_amdgcn_s_barrier();
  }

  #pragma unroll
  for (int t = 0; t < 2; ++t) {
    float l = li[t];
    l += __shfl_xor(l, 16);
    l += __shfl_xor(l, 32);
    const float inv = 1.0f / l;
    const size_t rowbase = ((size_t)(b * QL + q0 + t * 16 + lm)) * (NH * HD) + h * HD;
    #pragma unroll
    for (int dt = 0; dt < 8; ++dt) {
      bf16x4 v = mk4(o[t][dt][0] * inv, o[t][dt][1] * inv,
                     o[t][dt][2] * inv, o[t][dt][3] * inv);
      *(bf16x4*)(ao + rowbase + dt * 16 + quad * 4) = v;
    }
  }
}

// ---------------------------------------------------------------------------
extern "C" void kernel_launch(void* const* d_in, const int* in_sizes, int n_in,
                              void* d_out, int out_size, void* d_ws, size_t ws_size,
                              hipStream_t stream) {
  const float* noise = (const float*)d_in[0];
  const float* ctx   = (const float*)d_in[1];
  const float* cosb  = (const float*)d_in[2];
  const float* sinb  = (const float*)d_in[3];
  const float* Wq    = (const float*)d_in[4];
  const float* Wk    = (const float*)d_in[5];
  const float* Wv    = (const float*)d_in[6];
  const float* Wo    = (const float*)d_in[7];
  const float* qn    = (const float*)d_in[8];
  const float* kn    = (const float*)d_in[9];
  float* out = (float*)d_out;

  char* ws = (char*)d_ws;
  // kvin: 64 MB [0,64M).  aob aliases kvin[0:16M) (kvin dead after V-proj).
  unsigned short* kvin = (unsigned short*)(ws);
  unsigned short* aob  = (unsigned short*)(ws);
  unsigned short* WqT  = (unsigned short*)(ws + 67108864);            //  8 MB
  unsigned short* WkT  = (unsigned short*)(ws + 67108864 + 8388608);  //  2 MB
  unsigned short* WvT  = (unsigned short*)(ws + 67108864 + 10485760); //  2 MB
  unsigned short* WoT  = (unsigned short*)(ws + 67108864 + 12582912); //  8 MB
  unsigned short* qbuf = (unsigned short*)(ws + 67108864 + 20971520); // 16 MB
  unsigned short* kbuf = (unsigned short*)(ws + 67108864 + 37748736); // 16 MB
  unsigned short* vtb  = (unsigned short*)(ws + 67108864 + 54525952); // 16 MB (total 132 MB)

  prep<<<dim3((B_ * KL * H_) / 8 / 256), dim3(256), 0, stream>>>(noise, ctx, kvin);

  wtrans<<<dim3(1024), dim3(256), 0, stream>>>(Wq, WqT, 2048, 2048);
  wtrans<<<dim3(256),  dim3(256), 0, stream>>>(Wk, WkT, 2048, 512);
  wtrans<<<dim3(256),  dim3(256), 0, stream>>>(Wv, WvT, 2048, 512);
  wtrans<<<dim3(1024), dim3(256), 0, stream>>>(Wo, WoT, 2048, 2048);

  gemm2<0><<<dim3(32 * 16), dim3(256), 0, stream>>>(
      kvin, WqT, qn, cosb, sinb, qbuf, nullptr);
  gemm2<1><<<dim3(128 * 4), dim3(256), 0, stream>>>(
      kvin, WkT, kn, cosb, sinb, kbuf, nullptr);
  gemm2<2><<<dim3(128 * 4), dim3(256), 0, stream>>>(
      kvin, WvT, nullptr, nullptr, nullptr, vtb, nullptr);

  attn2<<<dim3(512), dim3(256), 0, stream>>>(qbuf, kbuf, vtb, aob);

  gemm2<3><<<dim3(32 * 16), dim3(256), 0, stream>>>(
      aob, WoT, nullptr, nullptr, nullptr, nullptr, out);
}